// Round 2
// baseline (1519.028 us; speedup 1.0000x reference)
//
#include <hip/hip_runtime.h>
#include <stdint.h>

#define M_TOTAL 65536
#define IN_DIM 512
#define OBS_DIM 515
#define H_DIM 1024

typedef __bf16 bf16x8 __attribute__((ext_vector_type(8)));
typedef float f32x4 __attribute__((ext_vector_type(4)));
typedef unsigned short u16x8 __attribute__((ext_vector_type(8)));

__device__ __forceinline__ unsigned short f2bf(float f) {
  unsigned u = __float_as_uint(f);
  u = (u + 0x7FFFu + ((u >> 16) & 1u)) >> 16;  // RNE
  return (unsigned short)u;
}
__device__ __forceinline__ float bf2f(unsigned short h) {
  return __uint_as_float(((unsigned)h) << 16);
}
__device__ __forceinline__ float fast_tanh(float z) {
  float e = __expf(2.0f * z);
  return 1.0f - 2.0f / (e + 1.0f);
}
__device__ __forceinline__ void gl16(const void* g, void* l) {
  __builtin_amdgcn_global_load_lds(
      (__attribute__((address_space(1))) void*)g,
      (__attribute__((address_space(3))) void*)l, 16, 0, 0);
}

// ---------------- prep kernels ----------------
__global__ __launch_bounds__(256) void cast_f32_bf16(
    const float* __restrict__ src, unsigned short* __restrict__ dst, int n) {
  int i = blockIdx.x * 256 + threadIdx.x;
  int stride = gridDim.x * 256;
  for (; i < n; i += stride) dst[i] = f2bf(src[i]);
}

__global__ __launch_bounds__(256) void mask_kernel(
    const float* __restrict__ obs, unsigned char* __restrict__ mask) {
  int r = blockIdx.x * 256 + threadIdx.x;
  if (r < M_TOTAL) {
    const float* g = obs + (size_t)r * OBS_DIM + IN_DIM;
    bool m = (fabsf(g[0]) <= 0.1f) && (fabsf(g[1]) <= 0.1f) && (fabsf(g[2]) <= 0.1f);
    mask[r] = m ? 1 : 0;
  }
}

__global__ __launch_bounds__(256) void prep_x(
    const float* __restrict__ obs, unsigned short* __restrict__ x, int row0) {
  int g = blockIdx.x * 256 + threadIdx.x;  // over C*512
  int row = g >> 9, col = g & 511;
  x[g] = f2bf(obs[(size_t)(row0 + row) * OBS_DIM + col]);
}

// ---------------- main GEMM: C = tanh(A @ B^T + bias), bf16 in/out, f32 accum
// A: [M][lda] bf16, B: [N][K] bf16 (row-major = B^T form), tile 128x128, BK=32
__global__ __launch_bounds__(256) void gemm_bt_tanh(
    const unsigned short* __restrict__ A, int lda,
    const unsigned short* __restrict__ B,
    const float* __restrict__ bias,
    unsigned short* __restrict__ C, int ldc, int K)
{
  __shared__ alignas(16) unsigned short sA[128 * 32];
  __shared__ alignas(16) unsigned short sB[128 * 32];
  const int tid = threadIdx.x;
  const int lane = tid & 63;
  const int wv = tid >> 6;
  const int wm = wv >> 1, wn = wv & 1;
  const int m0 = blockIdx.y << 7;
  const int n0 = blockIdx.x << 7;
  const int lr = lane & 15;
  const int lk = lane >> 4;

  const f32x4 zero = {0.f, 0.f, 0.f, 0.f};
  f32x4 acc[4][4];
#pragma unroll
  for (int i = 0; i < 4; ++i)
#pragma unroll
    for (int j = 0; j < 4; ++j) acc[i][j] = zero;

  for (int kt = 0; kt < K; kt += 32) {
    __syncthreads();
#pragma unroll
    for (int r = 0; r < 2; ++r) {
      int q = (r << 8) + tid;        // 0..511
      int row = q >> 2;              // 0..127
      int col = (q & 3) << 3;        // 0,8,16,24
      int dst = (q & ~63) << 3;      // wave-uniform LDS base (elements)
      gl16(A + (size_t)(m0 + row) * lda + kt + col, &sA[dst]);
      gl16(B + (size_t)(n0 + row) * K + kt + col, &sB[dst]);
    }
    __syncthreads();
    bf16x8 af[4], bfr[4];
#pragma unroll
    for (int i = 0; i < 4; ++i)
      af[i] = *(const bf16x8*)&sA[((wm << 6) + (i << 4) + lr) * 32 + (lk << 3)];
#pragma unroll
    for (int j = 0; j < 4; ++j)
      bfr[j] = *(const bf16x8*)&sB[((wn << 6) + (j << 4) + lr) * 32 + (lk << 3)];
#pragma unroll
    for (int i = 0; i < 4; ++i)
#pragma unroll
      for (int j = 0; j < 4; ++j)
        acc[i][j] = __builtin_amdgcn_mfma_f32_16x16x32_bf16(af[i], bfr[j], acc[i][j], 0, 0, 0);
  }

  const int crow = m0 + (wm << 6);
  const int ccol = n0 + (wn << 6);
#pragma unroll
  for (int j = 0; j < 4; ++j) {
    int col = ccol + (j << 4) + lr;
    float bv = bias[col];
#pragma unroll
    for (int i = 0; i < 4; ++i) {
#pragma unroll
      for (int r = 0; r < 4; ++r) {
        int row = crow + (i << 4) + (lk << 2) + r;
        C[(size_t)row * ldc + col] = f2bf(fast_tanh(acc[i][j][r] + bv));
      }
    }
  }
}

// ---------------- layer3 policy: logits = H2 @ W3^T + b3 -> softmax(128) -> masked write
__global__ __launch_bounds__(256) void l3_policy(
    const unsigned short* __restrict__ H2,   // [C][1024] bf16
    const unsigned short* __restrict__ W3,   // [128][1024] bf16
    const float* __restrict__ b3,
    const unsigned char* __restrict__ mask,
    float* __restrict__ out_pi,              // full pi base (f32)
    int row0, int half, int sel)
{
  __shared__ alignas(16) unsigned short sA[128 * 32];
  __shared__ alignas(16) unsigned short sB[128 * 32];
  const int tid = threadIdx.x;
  const int lane = tid & 63;
  const int wv = tid >> 6;
  const int lr = lane & 15;
  const int lk = lane >> 4;
  const int m0 = blockIdx.x << 7;

  const f32x4 zero = {0.f, 0.f, 0.f, 0.f};
  f32x4 acc[2][8];
#pragma unroll
  for (int i = 0; i < 2; ++i)
#pragma unroll
    for (int j = 0; j < 8; ++j) acc[i][j] = zero;

  for (int kt = 0; kt < 1024; kt += 32) {
    __syncthreads();
#pragma unroll
    for (int r = 0; r < 2; ++r) {
      int q = (r << 8) + tid;
      int row = q >> 2;
      int col = (q & 3) << 3;
      int dst = (q & ~63) << 3;
      gl16(H2 + (size_t)(m0 + row) * 1024 + kt + col, &sA[dst]);
      gl16(W3 + (size_t)row * 1024 + kt + col, &sB[dst]);
    }
    __syncthreads();
    bf16x8 af[2], bfr[8];
#pragma unroll
    for (int i = 0; i < 2; ++i)
      af[i] = *(const bf16x8*)&sA[((wv << 5) + (i << 4) + lr) * 32 + (lk << 3)];
#pragma unroll
    for (int j = 0; j < 8; ++j)
      bfr[j] = *(const bf16x8*)&sB[((j << 4) + lr) * 32 + (lk << 3)];
#pragma unroll
    for (int i = 0; i < 2; ++i)
#pragma unroll
      for (int j = 0; j < 8; ++j)
        acc[i][j] = __builtin_amdgcn_mfma_f32_16x16x32_bf16(af[i], bfr[j], acc[i][j], 0, 0, 0);
  }

  float bv[8];
#pragma unroll
  for (int j = 0; j < 8; ++j) bv[j] = b3[(j << 4) + lr];

#pragma unroll
  for (int i = 0; i < 2; ++i) {
#pragma unroll
    for (int r = 0; r < 4; ++r) {
      float lg[8];
      float mx = -3.4e38f;
#pragma unroll
      for (int j = 0; j < 8; ++j) { lg[j] = acc[i][j][r] + bv[j]; mx = fmaxf(mx, lg[j]); }
#pragma unroll
      for (int d = 1; d < 16; d <<= 1) mx = fmaxf(mx, __shfl_xor(mx, d));
      float s = 0.f;
#pragma unroll
      for (int j = 0; j < 8; ++j) { lg[j] = __expf(lg[j] - mx); s += lg[j]; }
#pragma unroll
      for (int d = 1; d < 16; d <<= 1) s += __shfl_xor(s, d);
      float inv = 1.f / s;
      int grow = row0 + m0 + (wv << 5) + (i << 4) + (lk << 2) + r;
      bool wr = (mask[grow] != 0) == (sel != 0);
      size_t base = (size_t)grow * 256 + half;
#pragma unroll
      for (int j = 0; j < 8; ++j)
        out_pi[base + (j << 4) + lr] = wr ? (lg[j] * inv) : 0.0f;
    }
  }
}

// ---------------- layer3 value: v = H2v . w3 + b (wave per row, fp32 weights)
__global__ __launch_bounds__(256) void l3_value(
    const unsigned short* __restrict__ H2,
    const float* __restrict__ w3,
    const float* __restrict__ b3,
    float* __restrict__ out_v, int row0, int C)
{
  const int lane = threadIdx.x & 63;
  const int row = (blockIdx.x << 2) + (threadIdx.x >> 6);
  if (row >= C) return;
  float s = 0.f;
#pragma unroll
  for (int it = 0; it < 2; ++it) {
    int k = (it << 9) + (lane << 3);
    u16x8 h = *(const u16x8*)(H2 + (size_t)row * 1024 + k);
    const float4* wp = (const float4*)(w3 + k);
    float4 w0 = wp[0], w1 = wp[1];
    s += bf2f(h[0]) * w0.x + bf2f(h[1]) * w0.y + bf2f(h[2]) * w0.z + bf2f(h[3]) * w0.w;
    s += bf2f(h[4]) * w1.x + bf2f(h[5]) * w1.y + bf2f(h[6]) * w1.z + bf2f(h[7]) * w1.w;
  }
#pragma unroll
  for (int d = 1; d < 64; d <<= 1) s += __shfl_xor(s, d);
  if (lane == 0) out_v[row0 + row] = s + b3[0];
}

extern "C" void kernel_launch(void* const* d_in, const int* in_sizes, int n_in,
                              void* d_out, int out_size, void* d_ws, size_t ws_size,
                              hipStream_t stream)
{
  (void)in_sizes; (void)n_in; (void)out_size;
  const float* obs   = (const float*)d_in[0];
  const float* pf_w1 = (const float*)d_in[3];
  const float* pf_b1 = (const float*)d_in[4];
  const float* pf_w2 = (const float*)d_in[5];
  const float* pf_b2 = (const float*)d_in[6];
  const float* pf_w3 = (const float*)d_in[7];
  const float* pf_b3 = (const float*)d_in[8];
  const float* pc_w1 = (const float*)d_in[9];
  const float* pc_b1 = (const float*)d_in[10];
  const float* pc_w2 = (const float*)d_in[11];
  const float* pc_b2 = (const float*)d_in[12];
  const float* pc_w3 = (const float*)d_in[13];
  const float* pc_b3 = (const float*)d_in[14];
  const float* v_w1  = (const float*)d_in[15];
  const float* v_b1  = (const float*)d_in[16];
  const float* v_w2  = (const float*)d_in[17];
  const float* v_b2  = (const float*)d_in[18];
  const float* v_w3  = (const float*)d_in[19];
  const float* v_b3  = (const float*)d_in[20];

  float* out_pi = (float*)d_out;                       // f32 per reference output dtype
  float* out_v  = out_pi + (size_t)M_TOTAL * 256;

  // ws layout: bf16 weights (9.96 MB) | mask (64 KB) | x chunk | h1 | h2
  char* ws = (char*)d_ws;
  unsigned short* wPF1 = (unsigned short*)ws;
  unsigned short* wPC1 = wPF1 + 524288;
  unsigned short* wV1  = wPC1 + 524288;
  unsigned short* wPF2 = wV1  + 524288;
  unsigned short* wPC2 = wPF2 + 1048576;
  unsigned short* wV2  = wPC2 + 1048576;
  unsigned short* wPF3 = wV2  + 1048576;
  unsigned short* wPC3 = wPF3 + 131072;
  unsigned char*  maskp = (unsigned char*)(wPC3 + 131072);
  unsigned short* xb   = (unsigned short*)(maskp + 65536);

  // choose chunk size C by what fits: footprint = 10,027,008 + C*5120 bytes
  const size_t fixed = 10027008;
  int C = 1024;
  if      (ws_size >= fixed + 16384ull * 5120) C = 16384;
  else if (ws_size >= fixed +  8192ull * 5120) C = 8192;
  else if (ws_size >= fixed +  4096ull * 5120) C = 4096;
  else if (ws_size >= fixed +  2048ull * 5120) C = 2048;
  const int nchunk = M_TOTAL / C;

  unsigned short* h1 = xb + (size_t)C * 512;
  unsigned short* h2 = h1 + (size_t)C * 1024;

  cast_f32_bf16<<<512, 256, 0, stream>>>(pf_w1, wPF1, 524288);
  cast_f32_bf16<<<512, 256, 0, stream>>>(pc_w1, wPC1, 524288);
  cast_f32_bf16<<<512, 256, 0, stream>>>(v_w1,  wV1,  524288);
  cast_f32_bf16<<<1024, 256, 0, stream>>>(pf_w2, wPF2, 1048576);
  cast_f32_bf16<<<1024, 256, 0, stream>>>(pc_w2, wPC2, 1048576);
  cast_f32_bf16<<<1024, 256, 0, stream>>>(v_w2,  wV2,  1048576);
  cast_f32_bf16<<<256, 256, 0, stream>>>(pf_w3, wPF3, 131072);
  cast_f32_bf16<<<256, 256, 0, stream>>>(pc_w3, wPC3, 131072);
  mask_kernel<<<M_TOTAL / 256, 256, 0, stream>>>(obs, maskp);

  const dim3 gg(1024 / 128, C / 128);
  for (int c = 0; c < nchunk; ++c) {
    int row0 = c * C;
    prep_x<<<C * 512 / 256, 256, 0, stream>>>(obs, xb, row0);
    // policy-free MLP
    gemm_bt_tanh<<<gg, 256, 0, stream>>>(xb, 512, wPF1, pf_b1, h1, 1024, 512);
    gemm_bt_tanh<<<gg, 256, 0, stream>>>(h1, 1024, wPF2, pf_b2, h2, 1024, 1024);
    l3_policy<<<C / 128, 256, 0, stream>>>(h2, wPF3, pf_b3, maskp, out_pi, row0, 0, 1);
    // policy-con MLP
    gemm_bt_tanh<<<gg, 256, 0, stream>>>(xb, 512, wPC1, pc_b1, h1, 1024, 512);
    gemm_bt_tanh<<<gg, 256, 0, stream>>>(h1, 1024, wPC2, pc_b2, h2, 1024, 1024);
    l3_policy<<<C / 128, 256, 0, stream>>>(h2, wPC3, pc_b3, maskp, out_pi, row0, 128, 0);
    // value MLP
    gemm_bt_tanh<<<gg, 256, 0, stream>>>(xb, 512, wV1, v_b1, h1, 1024, 512);
    gemm_bt_tanh<<<gg, 256, 0, stream>>>(h1, 1024, wV2, v_b2, h2, 1024, 1024);
    l3_value<<<C / 4, 256, 0, stream>>>(h2, v_w3, v_b3, out_v, row0, C);
  }
}